// Round 2
// 363.130 us; speedup vs baseline: 1.7753x; 1.7753x over previous
//
#include <hip/hip_runtime.h>
#include <hip/hip_bf16.h>

typedef unsigned short u16;
typedef unsigned int   u32;

#define KPS     39
#define DIN     78
#define DHID    195
#define NTOKTOT (256*2048)

#define S1      104     // JND row stride (13 x 16B chunks, odd -> bank spread)
#define S2      232     // HN row stride (29 x 16B chunks, odd)
#define M1T     13      // 13 x 16 = 208 rows (DHID padded)
#define K1S     3       // 3 x 32 = 96  (DIN + bias col padded)
#define M2T     5       // 5 x 16 = 80 rows (DIN padded)
#define K2S     7       // 7 x 32 = 224 (DHID + bias col padded)
#define NW      8       // waves per block
#define TPI     (NW*16) // 128 tokens per block-iteration
#define TPB     2048    // tokens per block
#define NIT     (TPB/TPI)
#define NBLK    (NTOKTOT/TPB)   // 256 blocks = 1 per CU

// packed MFMA-fragment weight layouts: slot = (m*K + kt)*64 + lane, 16B each
#define W1F_E (M1T*K1S*64*8)    // 19968 u16 = 39936 B
#define W2F_E (M2T*K2S*64*8)    // 17920 u16 = 35840 B
#define JND_E (TPI*S1)          // 13312 u16 = 26624 B
#define HN_E  (TPI*S2)          // 29696 u16 = 59392 B
// + AB2 (78 float2) + B2C (78 f32) = 936 B  -> total 162728 <= 163840
#define SMEM_BYTES ((W1F_E+W2F_E+JND_E+HN_E)*2 + DIN*2*4 + DIN*4)

typedef __attribute__((ext_vector_type(8))) short short8;
typedef __attribute__((ext_vector_type(4))) float float4v;

static __device__ __forceinline__ u16 f2b(float v) {
  __hip_bfloat16 b = __float2bfloat16(v);
  return __builtin_bit_cast(u16, b);
}
static __device__ __forceinline__ float b2f(u16 u) {
  return __builtin_bit_cast(float, ((u32)u) << 16);
}

extern "C" __global__ __launch_bounds__(512, 2)
void fused_mlp_kernel(const float* __restrict__ xp,  const float* __restrict__ yp,
                      const float* __restrict__ W1p, const float* __restrict__ b1p,
                      const float* __restrict__ W2p, const float* __restrict__ b2p,
                      const float* __restrict__ a1p, const float* __restrict__ a2p,
                      const float* __restrict__ al1p,const float* __restrict__ be1p,
                      const float* __restrict__ al2p,const float* __restrict__ be2p,
                      float* __restrict__ out0, float* __restrict__ out1)
{
  extern __shared__ char smem[];
  u16*   W1F = (u16*)smem;            // packed A-fragments of W1 (+b1 col 78)
  u16*   W2F = W1F + W1F_E;           // packed A-fragments of W2*alpha1 (+bias col 195)
  u16*   JND = W2F + W2F_E;           // [128][S1] joined tokens bf16
  u16*   HN  = JND + JND_E;           // [128][S2] normalized hidden bf16
  float* AB2 = (float*)(HN + HN_E);   // interleaved alpha2/beta2
  float* B2C = AB2 + DIN*2;           // bias2 = b2 + W2*beta1

  const int tid  = threadIdx.x;
  const int lane = tid & 63;
  const int w    = tid >> 6;
  const int c    = lane & 15;   // A m-index / B n-index / C-D col (verified mapping)
  const int quad = lane >> 4;   // A/B k-block = quad*8 ; C/D row = quad*4+reg
  const int wr   = w * 16;
  const int blockTok = blockIdx.x * TPB;

  // ---- prefetch iteration-0 x/y into regs; lands while we stage weights ----
  float4v xr0, xr1, xr2, yr0, yr1, yr2;
  {
    const float4v* xw = (const float4v*)(xp + (size_t)(blockTok + wr) * KPS);
    const float4v* yw = (const float4v*)(yp + (size_t)(blockTok + wr) * KPS);
    xr0 = xw[lane];      yr0 = yw[lane];
    xr1 = xw[lane + 64]; yr1 = yw[lane + 64];
    if (lane < 28) { xr2 = xw[lane + 128]; yr2 = yw[lane + 128]; }
    else { xr2 = (float4v)0.f; yr2 = (float4v)0.f; }
  }

  // ---------------- one-time per-block staging ----------------
  // bias2 partial sums (4 threads per output d), scratch in (future) JND region
  {
    float* SCR = (float*)JND;
    if (tid < DIN*4) {
      int d = tid >> 2, p = tid & 3;
      float s = (p == 0) ? b2p[d] : 0.f;
      const float* wrow = W2p + d*DHID;
      for (int j = p; j < DHID; j += 4) s = __builtin_fmaf(wrow[j], be1p[j], s);
      SCR[tid] = s;
    }
  }
  __syncthreads();
  if (tid < DIN) {
    const float* SCR = (const float*)JND;
    B2C[tid] = SCR[4*tid] + SCR[4*tid+1] + SCR[4*tid+2] + SCR[4*tid+3];
    AB2[2*tid+0] = al2p[tid];
    AB2[2*tid+1] = be2p[tid];
  }
  // W1 fragments: row = m*16 + (lane&15), k = kt*32 + (lane>>4)*8 + e
  for (int s = tid; s < M1T*K1S*64; s += 512) {
    int m = s/(K1S*64), r = s - m*(K1S*64);
    int kt = r >> 6, l = r & 63;
    int cc = l & 15, qq = l >> 4;
    int row = m*16 + cc, k0 = kt*32 + qq*8;
    short8 v;
    #pragma unroll
    for (int e = 0; e < 8; ++e) {
      int k = k0 + e; float f = 0.f;
      if (row < DHID) { if (k < DIN) f = W1p[row*DIN + k]; else if (k == DIN) f = b1p[row]; }
      v[e] = (short)f2b(f);
    }
    *(short8*)&W1F[(size_t)s*8] = v;
  }
  __syncthreads();
  // W2 fragments (alpha1 folded; bias col at k=DHID from B2C); SCR now dead
  for (int s = tid; s < M2T*K2S*64; s += 512) {
    int m = s/(K2S*64), r = s - m*(K2S*64);
    int kt = r >> 6, l = r & 63;
    int cc = l & 15, qq = l >> 4;
    int d = m*16 + cc, k0 = kt*32 + qq*8;
    short8 v;
    #pragma unroll
    for (int e = 0; e < 8; ++e) {
      int k = k0 + e; float f = 0.f;
      if (d < DIN) {
        if (k < DHID)       f = W2p[d*DHID + k] * al1p[k];
        else if (k == DHID) f = B2C[d];
      }
      v[e] = (short)f2b(f);
    }
    *(short8*)&W2F[(size_t)s*8] = v;
  }
  // JND pad: col 78 = 1.0 (bias), cols 79..95 = 0 (read by kt=2)
  for (int i = tid; i < TPI*18; i += 512) {
    int t = i/18, cf = i - t*18;
    JND[t*S1 + DIN + cf] = (cf == 0) ? (u16)0x3F80 : (u16)0;
  }
  // HN pad: col 195 = 1.0 (bias), cols 196..223 = 0 (read by kt=6)
  for (int i = tid; i < TPI*29; i += 512) {
    int t = i/29, cf = i - t*29;
    HN[t*S2 + DHID + cf] = (cf == 0) ? (u16)0x3F80 : (u16)0;
  }
  __syncthreads();

  const float a1v = a1p[0];
  const float a2v = a2p[0];

  // precompute LDS offsets for the reg->JND scatter (loop-invariant)
  int joff[12];
  #pragma unroll
  for (int s = 0; s < 3; ++s) {
    int i4 = lane + s*64;
    #pragma unroll
    for (int k = 0; k < 4; ++k) {
      int idx = i4*4 + k;
      int t = idx / KPS, cc2 = idx - t*KPS;
      joff[s*4+k] = (wr + t)*S1 + cc2;
    }
  }

  const u16* pW1 = W1F + (size_t)lane*8;   // fragment reads: base + imm offsets
  const u16* pW2 = W2F + (size_t)lane*8;
  u16* pJ = JND + (wr + c)*S1;             // B-frag / residual row (this wave's tokens)
  u16* pH = HN  + (wr + c)*S2;

  #pragma unroll 1
  for (int it = 0; it < NIT; ++it) {
    const int tb = blockTok + it * TPI;

    // ---- scatter prefetched x/y regs into JND (bf16) ----
    #pragma unroll
    for (int k = 0; k < 4; ++k) {
      JND[joff[k]]         = f2b(xr0[k]);
      JND[joff[k] + KPS]   = f2b(yr0[k]);
      JND[joff[4+k]]       = f2b(xr1[k]);
      JND[joff[4+k] + KPS] = f2b(yr1[k]);
    }
    if (lane < 28) {
      #pragma unroll
      for (int k = 0; k < 4; ++k) {
        JND[joff[8+k]]       = f2b(xr2[k]);
        JND[joff[8+k] + KPS] = f2b(yr2[k]);
      }
    }

    // ---- issue next iteration's loads (hide HBM latency under the GEMMs) ----
    if (it + 1 < NIT) {
      const float4v* xw = (const float4v*)(xp + (size_t)(tb + TPI + wr) * KPS);
      const float4v* yw = (const float4v*)(yp + (size_t)(tb + TPI + wr) * KPS);
      xr0 = xw[lane];      yr0 = yw[lane];
      xr1 = xw[lane + 64]; yr1 = yw[lane + 64];
      if (lane < 28) { xr2 = xw[lane + 128]; yr2 = yw[lane + 128]; }
    }

    // ---- GEMM1: h[j][t] = sum_k W1[j][k] * JND[t][k] (bias via k=DIN col) ----
    float4v acc1[M1T];
    #pragma unroll
    for (int m = 0; m < M1T; ++m)
      #pragma unroll
      for (int q = 0; q < 4; ++q) acc1[m][q] = 0.f;

    #pragma unroll
    for (int kt = 0; kt < K1S; ++kt) {
      short8 bfr = *(const short8*)&pJ[kt*32 + quad*8];
      #pragma unroll
      for (int m = 0; m < M1T; ++m) {
        short8 afr = *(const short8*)&pW1[(m*K1S + kt)*512];
        acc1[m] = __builtin_amdgcn_mfma_f32_16x16x32_bf16(afr, bfr, acc1[m], 0, 0, 0);
      }
    }

    // ---- PReLU + LN1 over 195 (pad rows are exact 0) ----
    float sum = 0.f, ss = 0.f;
    #pragma unroll
    for (int m = 0; m < M1T; ++m)
      #pragma unroll
      for (int q = 0; q < 4; ++q) {
        float h = acc1[m][q];
        float p = fmaxf(h, 0.f) + a1v * fminf(h, 0.f);
        acc1[m][q] = p;
        sum += p;
        ss = __builtin_fmaf(p, p, ss);
      }
    sum += __shfl_xor(sum, 16, 64);
    sum += __shfl_xor(sum, 32, 64);
    ss  += __shfl_xor(ss,  16, 64);
    ss  += __shfl_xor(ss,  32, 64);
    const float mean = sum * (1.f/DHID);
    const float istd = rsqrtf(ss*(1.f/DHID) - mean*mean + 1e-5f);

    // store hn' = (p-mean)*istd (alpha1/beta1 folded into W2F); rows quad*4+reg
    #pragma unroll
    for (int m = 0; m < M1T; ++m) {
      int jb = m*16 + quad*4;
      if (m < 12) {
        ushort4 pk;
        pk.x = f2b((acc1[m][0] - mean)*istd);
        pk.y = f2b((acc1[m][1] - mean)*istd);
        pk.z = f2b((acc1[m][2] - mean)*istd);
        pk.w = f2b((acc1[m][3] - mean)*istd);
        *(ushort4*)&pH[jb] = pk;
      } else if (quad == 0) {          // rows 192..194 only; never touch bias col 195
        pH[192] = f2b((acc1[m][0] - mean)*istd);
        pH[193] = f2b((acc1[m][1] - mean)*istd);
        pH[194] = f2b((acc1[m][2] - mean)*istd);
      }
    }

    // ---- GEMM2: h2[d][t] = sum_k W2'[d][k] * HN[t][k] ----
    float4v acc2[M2T];
    #pragma unroll
    for (int m = 0; m < M2T; ++m)
      #pragma unroll
      for (int q = 0; q < 4; ++q) acc2[m][q] = 0.f;

    #pragma unroll
    for (int kt = 0; kt < K2S; ++kt) {
      short8 bfr = *(const short8*)&pH[kt*32 + quad*8];
      #pragma unroll
      for (int m = 0; m < M2T; ++m) {
        short8 afr = *(const short8*)&pW2[(m*K2S + kt)*512];
        acc2[m] = __builtin_amdgcn_mfma_f32_16x16x32_bf16(afr, bfr, acc2[m], 0, 0, 0);
      }
    }

    // ---- PReLU + LN2 + residual + store (f32 out) ----
    float sum2 = 0.f, ss2 = 0.f;
    #pragma unroll
    for (int m = 0; m < M2T; ++m)
      #pragma unroll
      for (int q = 0; q < 4; ++q) {
        float h = acc2[m][q];
        float p = fmaxf(h, 0.f) + a2v * fminf(h, 0.f);
        acc2[m][q] = p;
        sum2 += p;
        ss2 = __builtin_fmaf(p, p, ss2);
      }
    sum2 += __shfl_xor(sum2, 16, 64);
    sum2 += __shfl_xor(sum2, 32, 64);
    ss2  += __shfl_xor(ss2,  16, 64);
    ss2  += __shfl_xor(ss2,  32, 64);
    const float mean2 = sum2 * (1.f/DIN);
    const float istd2 = rsqrtf(ss2*(1.f/DIN) - mean2*mean2 + 1e-5f);

    const int gt = tb + wr + c;
    #pragma unroll
    for (int m = 0; m < M2T; ++m) {
      int d0 = m*16 + quad*4;            // rows d0..d0+3, token c
      if (d0 < DIN) {
        ushort4 res = *(const ushort4*)&pJ[d0];
        u16 rr[4] = {res.x, res.y, res.z, res.w};
        #pragma unroll
        for (int r = 0; r < 4; ++r) {
          int d = d0 + r;
          if (d < DIN) {
            float2 ab = *(const float2*)&AB2[2*d];
            float  v  = (acc2[m][r] - mean2)*istd2*ab.x + ab.y + b2f(rr[r]);
            if (d < KPS) out0[(size_t)gt*KPS + d]         = v;
            else         out1[(size_t)gt*KPS + (d - KPS)] = v;
          }
        }
      }
    }
  }
}

extern "C" void kernel_launch(void* const* d_in, const int* in_sizes, int n_in,
                              void* d_out, int out_size, void* d_ws, size_t ws_size,
                              hipStream_t stream) {
  const float* xp   = (const float*)d_in[0];
  const float* yp   = (const float*)d_in[1];
  const float* W1p  = (const float*)d_in[2];
  const float* b1p  = (const float*)d_in[3];
  const float* W2p  = (const float*)d_in[4];
  const float* b2p  = (const float*)d_in[5];
  const float* a1p  = (const float*)d_in[6];
  const float* a2p  = (const float*)d_in[7];
  const float* al1p = (const float*)d_in[8];
  const float* be1p = (const float*)d_in[9];
  const float* al2p = (const float*)d_in[10];
  const float* be2p = (const float*)d_in[11];

  float* out0 = (float*)d_out;
  float* out1 = out0 + (size_t)NTOKTOT * KPS;

  hipFuncSetAttribute((const void*)fused_mlp_kernel,
                      hipFuncAttributeMaxDynamicSharedMemorySize, SMEM_BYTES);

  fused_mlp_kernel<<<NBLK, 512, SMEM_BYTES, stream>>>(
      xp, yp, W1p, b1p, W2p, b2p, a1p, a2p, al1p, be1p, al2p, be2p, out0, out1);
}